// Round 8
// baseline (1307.354 us; speedup 1.0000x reference)
//
#include <hip/hip_runtime.h>

#define NBLK 256              // one block per CU -> all co-resident
#define N_ITERS 20
#define SHIFT 5.0f            // t' = exp(-10*D + 5); e^5 cancels in t/S

typedef _Float16 h8 __attribute__((ext_vector_type(8)));
typedef float    f8 __attribute__((ext_vector_type(8)));

__device__ __forceinline__ float wave_allsum(float s) {
#pragma unroll
    for (int off = 1; off < 64; off <<= 1) s += __shfl_xor(s, off, 64);
    return s;
}
__device__ __forceinline__ float4 f4add(float4 a, float4 b) {
    return make_float4(a.x + b.x, a.y + b.y, a.z + b.z, a.w + b.w);
}
// Coherent accessors for cross-block data (LLC coherence point, no fences).
__device__ __forceinline__ void cstore(float* p, float v) {
    __hip_atomic_store(p, v, __ATOMIC_RELAXED, __HIP_MEMORY_SCOPE_AGENT);
}
__device__ __forceinline__ float cload(const float* p) {
    return __hip_atomic_load(p, __ATOMIC_RELAXED, __HIP_MEMORY_SCOPE_AGENT);
}

// Workspace is poisoned between runs: zero the per-iteration arrival counters.
__global__ void init_ctr(unsigned* __restrict__ ctr) {
    __hip_atomic_store(&ctr[threadIdx.x], 0u, __ATOMIC_RELAXED, __HIP_MEMORY_SCOPE_AGENT);
}

// R6-proven grid barrier: per-iteration counter slot, relaxed atomics, no
// cache-flush fences (cross-block data moves via coherent sc-bit accesses).
__device__ __forceinline__ void grid_barrier(unsigned* c, int tid) {
    asm volatile("s_waitcnt vmcnt(0)" ::: "memory");  // drain this wave's stores
    __syncthreads();                                   // all waves drained
    if (tid == 0) {
        __hip_atomic_fetch_add(c, 1u, __ATOMIC_RELAXED, __HIP_MEMORY_SCOPE_AGENT);
        int guard = 0;
        while (__hip_atomic_load(c, __ATOMIC_RELAXED, __HIP_MEMORY_SCOPE_AGENT) < NBLK &&
               guard < (1 << 24)) {       // bail out: fail, don't hang
            __builtin_amdgcn_s_sleep(2);
            ++guard;
        }
    }
    __syncthreads();
}

// 1024 threads = 16 waves = 8 row-groups x 2 column-halves.
// Each wave: 16 rows x 512 cols (8 cols/lane). Live set ~50-60 VGPRs -> fits
// the 64-VGPR budget the backend pins for 1024-thread workgroups (R1-R6:
// every larger layout spilled ~290 B/thread/iter and ran traffic-bound).
__global__ __launch_bounds__(1024) void
sinkhorn_persist(const float* __restrict__ D, float* __restrict__ Pg,
                 float* __restrict__ Qg, unsigned* __restrict__ ctr,
                 float* __restrict__ out) {
    __shared__ __align__(16) _Float16 eH[8][8][1024];   // 128 KB: rows 0..7/group
    __shared__ __align__(16) float4 sbuf4[1024];        // 16 KB: column tree
    __shared__ float evb[1024];                         // 4 KB
    __shared__ float sx[2][16];                         // half-row sum exchange

    const int b = blockIdx.x;
    const int bb = b >> 3, slab = b & 7;      // batch, 128-row slab
    const int tid = threadIdx.x;
    const int wave = tid >> 6, lane = tid & 63;
    const int g = wave >> 1, hf = wave & 1;   // row-group, column-half
    const int cb = (hf << 7) + (lane << 1);   // float4 index of lane's 8 cols
    const size_t rbase = (size_t)(bb << 10) + (slab << 7) + (g << 4);

    f8 ca, qa;
    float4 ev0 = make_float4(0, 0, 0, 0), ev1 = make_float4(0, 0, 0, 0);

#pragma unroll 1
    for (int it = 0; it < N_ITERS; ++it) {
        const bool last = (it == N_ITERS - 1);
        const bool build = (it == 0);
#pragma unroll
        for (int q = 0; q < 8; ++q) ca[q] = 0.f;
        if (last) {
#pragma unroll
            for (int q = 0; q < 8; ++q) qa[q] = 0.f;
        }
        if (!build) {
            ev0 = ((const float4*)evb)[cb];
            ev1 = ((const float4*)evb)[cb + 1];
        }

#pragma unroll
        for (int r = 0; r < 16; ++r) {
            h8 h;
            if (build || r >= 8) {
                // D read: build = compulsory HBM; iters = L2/LLC-resident
                const float4* D4 = (const float4*)(D + ((rbase + r) << 10));
                const float4 d0 = D4[cb], d1 = D4[cb + 1];
                h[0] = (_Float16)__expf(fmaf(d0.x, -10.f, SHIFT));
                h[1] = (_Float16)__expf(fmaf(d0.y, -10.f, SHIFT));
                h[2] = (_Float16)__expf(fmaf(d0.z, -10.f, SHIFT));
                h[3] = (_Float16)__expf(fmaf(d0.w, -10.f, SHIFT));
                h[4] = (_Float16)__expf(fmaf(d1.x, -10.f, SHIFT));
                h[5] = (_Float16)__expf(fmaf(d1.y, -10.f, SHIFT));
                h[6] = (_Float16)__expf(fmaf(d1.z, -10.f, SHIFT));
                h[7] = (_Float16)__expf(fmaf(d1.w, -10.f, SHIFT));
                if (build && r < 8)
                    ((h8*)&eH[g][r][0])[(hf << 6) + lane] = h;
            } else {
                h = ((const h8*)&eH[g][r][0])[(hf << 6) + lane];
            }
            f8 tf;
#pragma unroll
            for (int q = 0; q < 8; ++q) tf[q] = (float)h[q];
            float s;
            if (build) {        // ev == 1 on iteration 1
                s = ((tf[0] + tf[1]) + (tf[2] + tf[3]))
                  + ((tf[4] + tf[5]) + (tf[6] + tf[7]));
            } else {
                s = tf[0] * ev0.x + tf[1] * ev0.y + tf[2] * ev0.z + tf[3] * ev0.w
                  + tf[4] * ev1.x + tf[5] * ev1.y + tf[6] * ev1.z + tf[7] * ev1.w;
            }
            s = wave_allsum(s);                 // half-row sum
            if (lane == 0) sx[r & 1][wave] = s; // exchange with partner wave
            __syncthreads();
            const float sfull = sx[r & 1][g << 1] + sx[r & 1][(g << 1) + 1];
            const float rs = __builtin_amdgcn_rcpf(sfull);
#pragma unroll
            for (int q = 0; q < 8; ++q) ca[q] = fmaf(tf[q], rs, ca[q]);
            if (last) {
#pragma unroll
                for (int q = 0; q < 8; ++q)
                    qa[q] = fmaf(tf[q] * ((SHIFT - __logf(tf[q])) * 0.1f), rs, qa[q]);
            }
        }

        // ---- column reduction: 8 group-partials/column -> Pg (coherent) ----
        const int par = it & 1;     // parity double-buffer across iterations
        {
            __syncthreads();        // sbuf4 free
            const float4 m0 = make_float4(ca[0], ca[1], ca[2], ca[3]);
            const float4 m1 = make_float4(ca[4], ca[5], ca[6], ca[7]);
            if (g < 4) {
                sbuf4[(g << 8) + cb]     = m0;
                sbuf4[(g << 8) + cb + 1] = m1;
            }
            __syncthreads();
            if (g >= 4) {
                const int ix = ((g - 4) << 8) + cb;
                sbuf4[ix]     = f4add(sbuf4[ix],     m0);
                sbuf4[ix + 1] = f4add(sbuf4[ix + 1], m1);
            }
            __syncthreads();
            const float* sb = (const float*)sbuf4;
            const float cs = sb[tid] + sb[1024 + tid] + sb[2048 + tid] + sb[3072 + tid];
            cstore(&Pg[((par * NBLK + b) << 10) + tid], cs);
        }
        if (last) {
            __syncthreads();
            const float4 m0 = make_float4(qa[0], qa[1], qa[2], qa[3]);
            const float4 m1 = make_float4(qa[4], qa[5], qa[6], qa[7]);
            if (g < 4) {
                sbuf4[(g << 8) + cb]     = m0;
                sbuf4[(g << 8) + cb + 1] = m1;
            }
            __syncthreads();
            if (g >= 4) {
                const int ix = ((g - 4) << 8) + cb;
                sbuf4[ix]     = f4add(sbuf4[ix],     m0);
                sbuf4[ix + 1] = f4add(sbuf4[ix + 1], m1);
            }
            __syncthreads();
            const float* sb = (const float*)sbuf4;
            const float qs = sb[tid] + sb[1024 + tid] + sb[2048 + tid] + sb[3072 + tid];
            cstore(&Qg[(b << 10) + tid], qs);
            if (b == 0 && tid == 0) cstore(out, 0.f);   // arm final atomics
        }

        grid_barrier(&ctr[it], tid);

        if (!last) {
            // Redundant per-block ev: gather this batch's 8 partials (LLC).
            const float* Pb = Pg + ((par * NBLK + (bb << 3)) << 10) + tid;
            float s8 = 0.f;
#pragma unroll
            for (int j = 0; j < 8; ++j) s8 += cload(&Pb[j << 10]);
            evb[tid] = 1.0f / s8;
            __syncthreads();               // evb ready for next iteration
        } else if (slab == 0) {
            // loss = mean_b sum_m (sum_j Q[j][m]) / (sum_j P[j][m])
            const float* Pb = Pg + ((par * NBLK + (bb << 3)) << 10) + tid;
            const float* Qb = Qg + ((bb << 3) << 10) + tid;
            float s8 = 0.f, q8 = 0.f;
#pragma unroll
            for (int j = 0; j < 8; ++j) {
                s8 += cload(&Pb[j << 10]);
                q8 += cload(&Qb[j << 10]);
            }
            float c = q8 / s8;
            c = wave_allsum(c);
            if (lane == 0) sx[0][wave] = c;
            __syncthreads();
            if (tid == 0) {
                float tot = 0.f;
#pragma unroll
                for (int w = 0; w < 16; ++w) tot += sx[0][w];
                atomicAdd(out, tot * (1.0f / 32.0f));
            }
        }
    }
}

extern "C" void kernel_launch(void* const* d_in, const int* in_sizes, int n_in,
                              void* d_out, int out_size, void* d_ws, size_t ws_size,
                              hipStream_t stream) {
    const float* D = (const float*)d_in[0];
    float* out = (float*)d_out;

    unsigned* ctr = (unsigned*)d_ws;                    // 64 slots (zeroed below)
    float* Pg = (float*)((char*)d_ws + 1024);           // [2][256][1024] f32 = 2 MB
    float* Qg = Pg + 2 * NBLK * 1024;                   // [256][1024] f32 = 1 MB

    init_ctr<<<1, 64, 0, stream>>>(ctr);
    sinkhorn_persist<<<NBLK, 1024, 0, stream>>>(D, Pg, Qg, ctr, out);
}

// Round 9
// 995.529 us; speedup vs baseline: 1.3132x; 1.3132x over previous
//
#include <hip/hip_runtime.h>

#define NBLK 256              // one block per CU -> all co-resident
#define N_ITERS 20
#define SHIFT 5.0f            // t' = exp(-10*D + 5); e^5 cancels in t/S

typedef _Float16 h8 __attribute__((ext_vector_type(8)));
typedef float    f8 __attribute__((ext_vector_type(8)));

__device__ __forceinline__ float wave_allsum(float s) {
#pragma unroll
    for (int off = 1; off < 64; off <<= 1) s += __shfl_xor(s, off, 64);
    return s;
}
__device__ __forceinline__ float4 f4add(float4 a, float4 b) {
    return make_float4(a.x + b.x, a.y + b.y, a.z + b.z, a.w + b.w);
}
// Coherent accessors for cross-block data (LLC coherence point, no fences).
__device__ __forceinline__ void cstore(float* p, float v) {
    __hip_atomic_store(p, v, __ATOMIC_RELAXED, __HIP_MEMORY_SCOPE_AGENT);
}
__device__ __forceinline__ float cload(const float* p) {
    return __hip_atomic_load(p, __ATOMIC_RELAXED, __HIP_MEMORY_SCOPE_AGENT);
}

// Workspace is poisoned between runs: zero the per-iteration arrival counters.
__global__ void init_ctr(unsigned* __restrict__ ctr) {
    __hip_atomic_store(&ctr[threadIdx.x], 0u, __ATOMIC_RELAXED, __HIP_MEMORY_SCOPE_AGENT);
}

// In-block reduction of per-wave column partials (by value, conflict-free f4;
// consecutive-lane float4 indexing = 16B/lane, the standard wide pattern).
__device__ __forceinline__ float stage_colsum(f8 a0, f8 a1, float4* sbuf,
                                              int wave, int lane, int tid) {
    const int w4 = wave & 3;
    const float4 m0 = make_float4(a0[0], a0[1], a0[2], a0[3]);
    const float4 m1 = make_float4(a0[4], a0[5], a0[6], a0[7]);
    const float4 m2 = make_float4(a1[0], a1[1], a1[2], a1[3]);
    const float4 m3 = make_float4(a1[4], a1[5], a1[6], a1[7]);
    __syncthreads();                      // previous readers of sbuf are done
    const int i0 = (w4 << 8) + lane;
    if (wave < 4) {
        sbuf[i0]       = m0;
        sbuf[i0 + 64]  = m1;
        sbuf[i0 + 128] = m2;
        sbuf[i0 + 192] = m3;
    }
    __syncthreads();
#pragma unroll
    for (int g = 1; g < 4; ++g) {         // 3 serialized add rounds
        if ((wave >> 2) == g) {
            sbuf[i0]       = f4add(sbuf[i0],       m0);
            sbuf[i0 + 64]  = f4add(sbuf[i0 + 64],  m1);
            sbuf[i0 + 128] = f4add(sbuf[i0 + 128], m2);
            sbuf[i0 + 192] = f4add(sbuf[i0 + 192], m3);
        }
        __syncthreads();
    }
    const int rem = tid & 511, lt = rem >> 3, ut = rem & 7;
    const int ht = ((tid >> 9) << 1) + (ut >> 2), rt = ut & 3;
    const float* bf = (const float*)sbuf;
    float cs = 0.f;
#pragma unroll
    for (int w = 0; w < 4; ++w) cs += bf[(((w << 8) + (ht << 6) + lt) << 2) + rt];
    return cs;
}

// R6/R8-proven grid barrier: per-iteration counter slot, relaxed atomics,
// no cache-flush fences (cross-block data moves via coherent accesses).
__device__ __forceinline__ void grid_barrier(unsigned* c, int tid) {
    asm volatile("s_waitcnt vmcnt(0)" ::: "memory");  // drain this wave's stores
    __syncthreads();                                   // all waves drained
    if (tid == 0) {
        __hip_atomic_fetch_add(c, 1u, __ATOMIC_RELAXED, __HIP_MEMORY_SCOPE_AGENT);
        int guard = 0;
        while (__hip_atomic_load(c, __ATOMIC_RELAXED, __HIP_MEMORY_SCOPE_AGENT) < NBLK &&
               guard < (1 << 24)) {       // bail out: fail, don't hang
            __builtin_amdgcn_s_sleep(2);
            ++guard;
        }
    }
    __syncthreads();
}

#define EXP8(H, DA, DB)                                                        \
    (H)[0] = (_Float16)__expf(fmaf((DA).x, -10.f, SHIFT));                     \
    (H)[1] = (_Float16)__expf(fmaf((DA).y, -10.f, SHIFT));                     \
    (H)[2] = (_Float16)__expf(fmaf((DA).z, -10.f, SHIFT));                     \
    (H)[3] = (_Float16)__expf(fmaf((DA).w, -10.f, SHIFT));                     \
    (H)[4] = (_Float16)__expf(fmaf((DB).x, -10.f, SHIFT));                     \
    (H)[5] = (_Float16)__expf(fmaf((DB).y, -10.f, SHIFT));                     \
    (H)[6] = (_Float16)__expf(fmaf((DB).z, -10.f, SHIFT));                     \
    (H)[7] = (_Float16)__expf(fmaf((DB).w, -10.f, SHIFT));

#define SUM8(H) ((float)(H)[0] + (float)(H)[1] + (float)(H)[2] + (float)(H)[3] \
               + (float)(H)[4] + (float)(H)[5] + (float)(H)[6] + (float)(H)[7])

#define DOT8(H, A, B)                                                          \
    ((float)(H)[0]*(A).x + (float)(H)[1]*(A).y + (float)(H)[2]*(A).z +         \
     (float)(H)[3]*(A).w + (float)(H)[4]*(B).x + (float)(H)[5]*(B).y +         \
     (float)(H)[6]*(B).z + (float)(H)[7]*(B).w)

#define ACC8(CA, H, RS)                                                        \
    _Pragma("unroll")                                                          \
    for (int q = 0; q < 8; ++q) (CA)[q] = fmaf((float)(H)[q], (RS), (CA)[q]);

#define ACCQ8(CA, H, RS)                                                       \
    _Pragma("unroll")                                                          \
    for (int q = 0; q < 8; ++q) {                                              \
        const float tq = (float)(H)[q];                                        \
        (CA)[q] = fmaf(tq * ((SHIFT - __logf(tq)) * 0.1f), (RS), (CA)[q]);     \
    }

// Build one row from D (HBM, once), store fp16 to EPTR (LDS row or Eg row),
// and accumulate iteration-1 partials (ev == 1).
#define BUILD_ROW(RR, EPTR)                                                    \
    {                                                                          \
        const float4* D4 = (const float4*)(D + ((rbase + (RR)) << 10));        \
        const float4 d0 = D4[2 * lane],        d1 = D4[2 * lane + 1];          \
        h8 h0; EXP8(h0, d0, d1)                                                \
        const float4 d2 = D4[2 * (lane + 64)], d3 = D4[2 * (lane + 64) + 1];   \
        h8 h1; EXP8(h1, d2, d3)                                                \
        (EPTR)[lane] = h0; (EPTR)[lane + 64] = h1;                             \
        float s = SUM8(h0) + SUM8(h1);                                         \
        s = wave_allsum(s);                                                    \
        const float rs = __builtin_amdgcn_rcpf(s);                             \
        ACC8(ca0, h0, rs) ACC8(ca1, h1, rs)                                    \
        __builtin_amdgcn_sched_barrier(0);                                     \
    }

// One Sinkhorn row step from fp16 row at EPTR. ACCM in {ACC8, ACCQ8}.
// No block barriers anywhere in here: rows are wave-private.
#define ITER_ROW(EPTR, ACCM)                                                   \
    {                                                                          \
        const h8 h0 = (EPTR)[lane], h1 = (EPTR)[lane + 64];                    \
        const float4 g0 = evb4[lane],       g1 = evb4[64 + lane];              \
        const float4 g2 = evb4[128 + lane], g3 = evb4[192 + lane];             \
        float s = DOT8(h0, g0, g1) + DOT8(h1, g2, g3);                         \
        s = wave_allsum(s);                                                    \
        const float rs = __builtin_amdgcn_rcpf(s);                             \
        ACCM(ca0, h0, rs) ACCM(ca1, h1, rs)                                    \
        __builtin_amdgcn_sched_barrier(0);                                     \
    }

#define LROW(K) ((const h8*)eH[(wave << 2) + (K)])
#define GROW(K) ((const h8*)(Eg + ((egbase + (K)) << 10)))

// 16 waves, each owning 8 full rows: 4 in LDS fp16, 4 in a BLOCK-PRIVATE
// global fp16 scratch Eg (128 KB/block -> 4 MB/XCD = L2-resident, plain
// cached loads; only the owning block touches it). No persistent E registers:
// live set ~45-50 VGPRs, under the 64-VGPR budget the backend pins (R8
// proved fitting eliminates the spill traffic). No intra-iteration barriers.
__global__ __launch_bounds__(1024) void
sinkhorn_persist(const float* __restrict__ D, _Float16* __restrict__ Eg,
                 float* __restrict__ Pg, float* __restrict__ Qg,
                 unsigned* __restrict__ ctr, float* __restrict__ out) {
    __shared__ __align__(16) _Float16 eH[16 * 4][1024];   // 128 KB
    __shared__ __align__(16) float4 sbuf4[1024];          // 16 KB: column tree
    __shared__ __align__(16) float4 evb4[256];            // 4 KB (permuted)
    float* evb = (float*)evb4;

    const int b = blockIdx.x;
    const int bb = b >> 3, slab = b & 7;      // batch, 128-row slab
    const int tid = threadIdx.x;
    const int wave = tid >> 6, lane = tid & 63;
    const size_t rbase = ((size_t)bb << 10) + (slab << 7) + (wave << 3);
    const size_t egbase = ((size_t)b << 6) + (wave << 2);   // Eg row index

    f8 ca0, ca1;

#pragma unroll 1
    for (int it = 0; it < N_ITERS; ++it) {
        const bool last = (it == N_ITERS - 1);
#pragma unroll
        for (int q = 0; q < 8; ++q) { ca0[q] = 0.f; ca1[q] = 0.f; }

        if (it == 0) {
            BUILD_ROW(0, (h8*)eH[(wave << 2) + 0])
            BUILD_ROW(1, (h8*)eH[(wave << 2) + 1])
            BUILD_ROW(2, (h8*)eH[(wave << 2) + 2])
            BUILD_ROW(3, (h8*)eH[(wave << 2) + 3])
            BUILD_ROW(4, (h8*)(Eg + ((egbase + 0) << 10)))
            BUILD_ROW(5, (h8*)(Eg + ((egbase + 1) << 10)))
            BUILD_ROW(6, (h8*)(Eg + ((egbase + 2) << 10)))
            BUILD_ROW(7, (h8*)(Eg + ((egbase + 3) << 10)))
        } else {
            ITER_ROW(LROW(0), ACC8)
            ITER_ROW(LROW(1), ACC8)
            ITER_ROW(LROW(2), ACC8)
            ITER_ROW(LROW(3), ACC8)
            ITER_ROW(GROW(0), ACC8)
            ITER_ROW(GROW(1), ACC8)
            ITER_ROW(GROW(2), ACC8)
            ITER_ROW(GROW(3), ACC8)
        }

        // Column reduction -> one 4 KB coherent partial per block.
        const int par = it & 1;   // parity double-buffer (no 2nd barrier needed)
        const float cs = stage_colsum(ca0, ca1, sbuf4, wave, lane, tid);
        cstore(&Pg[((par * NBLK + b) << 10) + tid], cs);

        if (last) {
            // Second pass for the loss numerator, reusing ca registers as qa.
#pragma unroll
            for (int q = 0; q < 8; ++q) { ca0[q] = 0.f; ca1[q] = 0.f; }
            ITER_ROW(LROW(0), ACCQ8)
            ITER_ROW(LROW(1), ACCQ8)
            ITER_ROW(LROW(2), ACCQ8)
            ITER_ROW(LROW(3), ACCQ8)
            ITER_ROW(GROW(0), ACCQ8)
            ITER_ROW(GROW(1), ACCQ8)
            ITER_ROW(GROW(2), ACCQ8)
            ITER_ROW(GROW(3), ACCQ8)
            const float qs = stage_colsum(ca0, ca1, sbuf4, wave, lane, tid);
            cstore(&Qg[(b << 10) + tid], qs);
            if (b == 0 && tid == 0) cstore(out, 0.f);   // arm final atomics
        }

        grid_barrier(&ctr[it], tid);

        if (!last) {
            // Per-block ev: gather this batch's 8 partials (LLC-coherent),
            // store into PERMUTED evb (float4 slot layout matching ITER_ROW).
            const float* Pb = Pg + ((par * NBLK + (bb << 3)) << 10) + tid;
            float s8 = 0.f;
#pragma unroll
            for (int j = 0; j < 8; ++j) s8 += cload(&Pb[j << 10]);
            const float evv = 1.0f / s8;
            const int rem = tid & 511, lt = rem >> 3, ut = rem & 7;
            const int ht = ((tid >> 9) << 1) + (ut >> 2), rt = ut & 3;
            evb[(((ht << 6) + lt) << 2) + rt] = evv;
            __syncthreads();               // evb ready for next iteration
        } else if (slab == 0) {
            // loss = mean_b sum_m (sum_j Q[j][m]) / (sum_j P[j][m])
            const float* Pb = Pg + ((par * NBLK + (bb << 3)) << 10) + tid;
            const float* Qb = Qg + ((bb << 3) << 10) + tid;
            float s8 = 0.f, q8 = 0.f;
#pragma unroll
            for (int j = 0; j < 8; ++j) {
                s8 += cload(&Pb[j << 10]);
                q8 += cload(&Qb[j << 10]);
            }
            float c = q8 / s8;
            c = wave_allsum(c);
            if (lane == 0) ((float*)sbuf4)[wave] = c;
            __syncthreads();
            if (tid == 0) {
                float tot = 0.f;
#pragma unroll
                for (int w = 0; w < 16; ++w) tot += ((float*)sbuf4)[w];
                atomicAdd(out, tot * (1.0f / 32.0f));
            }
        }
    }
}

extern "C" void kernel_launch(void* const* d_in, const int* in_sizes, int n_in,
                              void* d_out, int out_size, void* d_ws, size_t ws_size,
                              hipStream_t stream) {
    const float* D = (const float*)d_in[0];
    float* out = (float*)d_out;

    unsigned* ctr = (unsigned*)d_ws;                    // 64 slots (zeroed below)
    float* Pg = (float*)((char*)d_ws + 1024);           // [2][256][1024] f32 = 2 MB
    float* Qg = Pg + 2 * NBLK * 1024;                   // [256][1024] f32 = 1 MB
    _Float16* Eg = (_Float16*)(Qg + NBLK * 1024);       // [256][64][1024] fp16 = 32 MB

    init_ctr<<<1, 64, 0, stream>>>(ctr);
    sinkhorn_persist<<<NBLK, 1024, 0, stream>>>(D, Eg, Pg, Qg, ctr, out);
}